// Round 5
// baseline (840.835 us; speedup 1.0000x reference)
//
#include <hip/hip_runtime.h>
#include <hip/hip_bf16.h>

#define NN 102400      // B*T*NODES
#define DD 64
#define EE 1638400
#define L1C 96
#define L2C 64
#define TT 32
#define NODESC 400
#define BB 8
#define SS 3200        // B*NODES
#define G4 256         // 4*D

// ---------------- workspace layout (floats) ----------------
// big block [0, 26,214,400): a1 | g1 | ent(csr), later overwritten by xg
#define OFF_A1   ((size_t)6553600)    // NN*64
#define OFF_G1   ((size_t)13107200)   // NN*96 -> ends 22,937,600
#define OFF_ENT  ((size_t)22937600)   // EE int2 (2*EE floats) -> ends 26,214,400
#define OFF_XG   ((size_t)0)          // NN*256
#define OFF_H2   ((size_t)26214400)   // NN*64
#define OFF_G2   ((size_t)32768000)   // NN*64
#define OFF_DIS  ((size_t)39321600)   // NN
#define OFF_ROFF ((size_t)39424000)   // NN+1 ints (padded)
#define OFF_CUR  ((size_t)39526416)   // NN ints
#define OFF_HL   ((size_t)39628816)   // SS*64
#define OFF_ST   ((size_t)39833616)   // 256   -> total 39,833,872 floats = 159.3 MB

__device__ __forceinline__ void fma4(float4& a, float s, const float4& w) {
    a.x = fmaf(s, w.x, a.x); a.y = fmaf(s, w.y, a.y);
    a.z = fmaf(s, w.z, a.z); a.w = fmaf(s, w.w, a.w);
}
__device__ __forceinline__ float rcp_f(float x) { return __builtin_amdgcn_rcpf(x); }
__device__ __forceinline__ float sigm_f(float x) {
    x = fminf(fmaxf(x, -30.f), 30.f);
    return rcp_f(1.f + __expf(-x));
}
__device__ __forceinline__ float tanh_f(float x) {
    x = fminf(fmaxf(x, -15.f), 15.f);
    float e = __expf(2.f * x);
    return (e - 1.f) * rcp_f(e + 1.f);
}
// Opaque def: compiler cannot sink/rematerialize the load that produced v.
__device__ __forceinline__ void pin4(float4& v) {
    asm volatile("" : "+v"(v.x), "+v"(v.y), "+v"(v.z), "+v"(v.w));
}

// ---------------- init: zero cursor (hist) + stats ----------------
__global__ void init_zero(int* cursor, float* st) {
    int idx = blockIdx.x * 256 + threadIdx.x;
    if (idx < NN) cursor[idx] = 0;
    if (blockIdx.x == 0 && threadIdx.x < 128) st[threadIdx.x] = 0.f;
}

// ---------------- normalization stats ----------------
__global__ __launch_bounds__(256) void col_sums(const float* __restrict__ x, float* __restrict__ st) {
    int c = threadIdx.x & 63;
    size_t i = (size_t)blockIdx.x * 256 + threadIdx.x;
    size_t stride = (size_t)gridDim.x * 256;
    float s = 0.f, q = 0.f;
    for (size_t e = i; e < (size_t)NN * 64; e += stride) {
        float v = x[e]; s += v; q = fmaf(v, v, q);
    }
    __shared__ float ls[128];
    if (threadIdx.x < 128) ls[threadIdx.x] = 0.f;
    __syncthreads();
    atomicAdd(&ls[c], s); atomicAdd(&ls[64 + c], q);
    __syncthreads();
    if (threadIdx.x < 128) atomicAdd(&st[threadIdx.x], ls[threadIdx.x]);
}

__global__ void finalize_stats(float* st) {
    int c = threadIdx.x;
    if (c < 64) {
        float s = st[c], q = st[64 + c];
        float mean = s / (float)NN;
        float var = (q - s * s / (float)NN) / (float)(NN - 1);
        st[128 + c] = mean;
        st[192 + c] = rsqrtf(fmaxf(var, 1e-20f));
    }
}

// ---------------- CSR build (dest-sorted, packed 8B entries) ----------------
__global__ void hist_acc(const int* __restrict__ ei, int* __restrict__ cnt) {
    int e = blockIdx.x * 256 + threadIdx.x;
    atomicAdd(&cnt[ei[EE + e]], 1);
}

// single-block exclusive scan over NN counts; writes roff[0..NN] and cursor[0..NN-1]
__global__ __launch_bounds__(1024) void scan_kernel(int* __restrict__ cnt, int* __restrict__ roff, int* __restrict__ cursor) {
    __shared__ int part[1024];
    int tid = threadIdx.x;
    int base = tid * (NN / 1024);
    int s = 0;
    for (int i = 0; i < NN / 1024; ++i) s += cnt[base + i];
    part[tid] = s;
    __syncthreads();
    for (int d = 1; d < 1024; d <<= 1) {
        int v = (tid >= d) ? part[tid - d] : 0;
        __syncthreads();
        part[tid] += v;
        __syncthreads();
    }
    int run = part[tid] - s;     // exclusive prefix of this thread's range
    for (int i = 0; i < NN / 1024; ++i) {
        int c = cnt[base + i];
        roff[base + i] = run;
        cursor[base + i] = run;
        run += c;
    }
    if (tid == 1023) roff[NN] = run;
}

__global__ void csr_fill(const int* __restrict__ ei, const float* __restrict__ ea,
                         int* __restrict__ cursor, int2* __restrict__ ent) {
    int e = blockIdx.x * 256 + threadIdx.x;
    int d = ei[EE + e];
    int pos = atomicAdd(&cursor[d], 1);
    ent[pos] = make_int2(ei[e], __float_as_int(fabsf(ea[2 * (size_t)e])));
}

// deg[n] = 1 + sum of raw weights in row n (self-loop weight 1); dis = rsqrt(deg)
__global__ void row_norm(const int* __restrict__ roff, const int2* __restrict__ ent, float* __restrict__ dis) {
    int n = blockIdx.x * 256 + threadIdx.x;
    int e0 = roff[n], e1 = roff[n + 1];
    float deg = 1.f;
    for (int e = e0; e < e1; ++e) deg += __int_as_float(ent[e].y);
    dis[n] = rsqrtf(deg);
}

// ---------------- tiled f32 GEMM ----------------
template<int K, int NC, int MB, int THREADS, bool PRELU, bool TRANSW, bool XGOUT>
__global__ __launch_bounds__(THREADS) void gemm_tiled(
    const float* __restrict__ A, const float* __restrict__ Wm,
    const float* __restrict__ bin, const float* __restrict__ bo1, const float* __restrict__ bo2,
    float* __restrict__ Cm, int ldC)
{
    __shared__ float As[MB * K];
    __shared__ float Ws[K * NC];
    const int cb0 = TRANSW ? ((int)blockIdx.y * NC) : 0;   // xg column-half select

    if (!TRANSW) {
        for (int i = threadIdx.x; i < K * NC / 4; i += THREADS)
            ((float4*)Ws)[i] = ((const float4*)Wm)[i];
    } else {
        for (int i = threadIdx.x; i < NC * (K / 4); i += THREADS) {
            int g = i / (K / 4); int d = (i % (K / 4)) * 4;
            float4 v = *(const float4*)(Wm + (size_t)(cb0 + g) * K + d);
            Ws[(d + 0) * NC + g] = v.x; Ws[(d + 1) * NC + g] = v.y;
            Ws[(d + 2) * NC + g] = v.z; Ws[(d + 3) * NC + g] = v.w;
        }
    }
    size_t row0 = (size_t)blockIdx.x * MB;
    for (int i = threadIdx.x; i < MB * (K / 4); i += THREADS) {
        int r = i / (K / 4); int c = (i % (K / 4)) * 4;
        float4 a = *(const float4*)(A + (row0 + r) * K + c);
        if (PRELU) {
            a.x = fmaxf(a.x + bin[c + 0], 0.f); a.y = fmaxf(a.y + bin[c + 1], 0.f);
            a.z = fmaxf(a.z + bin[c + 2], 0.f); a.w = fmaxf(a.w + bin[c + 3], 0.f);
        }
        ((float4*)As)[i] = a;
    }
    __syncthreads();

    constexpr int NCT = NC / 4;
    int tc = threadIdx.x % NCT;
    int tr = threadIdx.x / NCT;
    int r = tr * 4;
    float4 acc[4];
    acc[0] = acc[1] = acc[2] = acc[3] = make_float4(0.f, 0.f, 0.f, 0.f);

    #pragma unroll 8
    for (int d4 = 0; d4 < K / 4; ++d4) {
        float4 w0 = ((const float4*)Ws)[(4 * d4 + 0) * NCT + tc];
        float4 w1 = ((const float4*)Ws)[(4 * d4 + 1) * NCT + tc];
        float4 w2 = ((const float4*)Ws)[(4 * d4 + 2) * NCT + tc];
        float4 w3 = ((const float4*)Ws)[(4 * d4 + 3) * NCT + tc];
        #pragma unroll
        for (int i = 0; i < 4; ++i) {
            float4 av = ((const float4*)As)[(r + i) * (K / 4) + d4];
            fma4(acc[i], av.x, w0); fma4(acc[i], av.y, w1);
            fma4(acc[i], av.z, w2); fma4(acc[i], av.w, w3);
        }
    }

    if (!XGOUT) {
        #pragma unroll
        for (int i = 0; i < 4; ++i) {
            size_t row = row0 + r + i;
            *(float4*)(Cm + row * ldC + tc * 4) = acc[i];
        }
    } else {
        int cb = cb0 + tc * 4;
        float4 bs;
        bs.x = bo1[cb + 0] + bo2[cb + 0]; bs.y = bo1[cb + 1] + bo2[cb + 1];
        bs.z = bo1[cb + 2] + bo2[cb + 2]; bs.w = bo1[cb + 3] + bo2[cb + 3];
        #pragma unroll
        for (int i = 0; i < 4; ++i) {
            int n = (int)row0 + r + i;                      // n = b*T*NODES + t*NODES + node
            int b_ = n / (TT * NODESC);
            int rem = n - b_ * (TT * NODESC);
            int t = rem / NODESC;
            int node = rem - t * NODESC;
            int orow = (b_ * NODESC + node) * TT + t;       // seq-major, time inner
            float4 o = acc[i];
            o.x += bs.x; o.y += bs.y; o.z += bs.z; o.w += bs.w;
            *(float4*)(Cm + (size_t)orow * ldC + cb) = o;
        }
    }
}

// ---------------- GCN aggregation: gather over packed CSR, dis folded in ----------------
// g[n] = dis[n] * ( dis[n]*h[n] + sum_e w_e*dis[src_e]*h[src_e] )
// NORM variant normalizes h rows on the fly from raw x + column stats (saves xn round-trip).
template<int C4, bool NORM>
__global__ __launch_bounds__(256) void gcn_gather(const float* __restrict__ h, const int* __restrict__ roff,
                                                  const int2* __restrict__ ent, const float* __restrict__ dis,
                                                  const float* __restrict__ st, float* __restrict__ g) {
    unsigned int idx = blockIdx.x * 256 + threadIdx.x;
    unsigned int n = idx / C4, q = idx % C4;
    float4 mean4, istd4;
    if (NORM) {
        mean4 = ((const float4*)(st + 128))[q];
        istd4 = ((const float4*)(st + 192))[q];
    }
    float dn = dis[n];
    float4 acc = ((const float4*)h)[(size_t)n * C4 + q];
    if (NORM) {
        acc.x = (acc.x - mean4.x) * istd4.x; acc.y = (acc.y - mean4.y) * istd4.y;
        acc.z = (acc.z - mean4.z) * istd4.z; acc.w = (acc.w - mean4.w) * istd4.w;
    }
    acc.x *= dn; acc.y *= dn; acc.z *= dn; acc.w *= dn;
    int e0 = roff[n], e1 = roff[n + 1];
    for (int e = e0; e < e1; ++e) {
        int2 en = ent[e];
        float w = __int_as_float(en.y) * dis[en.x];
        float4 v = ((const float4*)h)[(size_t)en.x * C4 + q];
        if (NORM) {
            v.x = (v.x - mean4.x) * istd4.x; v.y = (v.y - mean4.y) * istd4.y;
            v.z = (v.z - mean4.z) * istd4.z; v.w = (v.w - mean4.w) * istd4.w;
        }
        fma4(acc, w, v);
    }
    acc.x *= dn; acc.y *= dn; acc.z *= dn; acc.w *= dn;
    ((float4*)g)[(size_t)n * C4 + q] = acc;
}

// ---------------- LSTM (recurrent part; xg precomputed) ----------------
// 256 threads = 4 waves; 8 seqs/block. Thread tid owns gate-row tid for ALL 8 seqs
// (w_hh row pinned in 64 VGPRs via inline-asm). xg loads software-pipelined one
// t-iteration ahead. Activation: wave w handles seqs 2w, 2w+1.
#define STEPK(i, wv) { float4 hv = hq[i]; \
    acc.x = fmaf(hv.x, wv.x, acc.x); acc.y = fmaf(hv.y, wv.y, acc.y); \
    acc.z = fmaf(hv.z, wv.z, acc.z); acc.w = fmaf(hv.w, wv.w, acc.w); }
#define DOTQ(qq, xv) { const float4* hq = (const float4*)hs[qq]; \
    float4 acc = make_float4(0.f, 0.f, 0.f, 0.f); \
    STEPK(0,r0) STEPK(1,r1) STEPK(2,r2) STEPK(3,r3) STEPK(4,r4) STEPK(5,r5) STEPK(6,r6) STEPK(7,r7) \
    STEPK(8,r8) STEPK(9,r9) STEPK(10,r10) STEPK(11,r11) STEPK(12,r12) STEPK(13,r13) STEPK(14,r14) STEPK(15,r15) \
    gp[qq][tid] = (xv) + (acc.x + acc.y) + (acc.z + acc.w); }

__global__ __launch_bounds__(256, 1) void lstm_kernel(const float* __restrict__ xg, const float* __restrict__ whh,
                                                      float* __restrict__ hlast) {
    __shared__ float hs[8][64];
    __shared__ float gp[8][256];
    const int tid = threadIdx.x;
    const int w = tid >> 6, j = tid & 63;
    const float4* wr = (const float4*)(whh + (size_t)tid * 64);
    float4 r0 = wr[0],  r1 = wr[1],  r2 = wr[2],  r3 = wr[3];
    float4 r4 = wr[4],  r5 = wr[5],  r6 = wr[6],  r7 = wr[7];
    float4 r8 = wr[8],  r9 = wr[9],  r10 = wr[10], r11 = wr[11];
    float4 r12 = wr[12], r13 = wr[13], r14 = wr[14], r15 = wr[15];
    pin4(r0); pin4(r1); pin4(r2); pin4(r3); pin4(r4); pin4(r5); pin4(r6); pin4(r7);
    pin4(r8); pin4(r9); pin4(r10); pin4(r11); pin4(r12); pin4(r13); pin4(r14); pin4(r15);
    float c0 = 0.f, c1 = 0.f, h0 = 0.f, h1 = 0.f;
    ((float*)hs)[tid] = 0.f; ((float*)hs)[256 + tid] = 0.f;
    const float* xb = xg + (size_t)blockIdx.x * 8 * TT * G4 + tid;
    float xv[8];
    #pragma unroll
    for (int q = 0; q < 8; ++q) xv[q] = xb[(q * TT) * G4];
    __syncthreads();
    for (int t = 0; t < TT; ++t) {
        // prefetch next step's gate inputs (consumed next iteration)
        const int tn = (t + 1 < TT) ? t + 1 : t;
        float xn8[8];
        #pragma unroll
        for (int q = 0; q < 8; ++q) xn8[q] = xb[(q * TT + tn) * G4];
        DOTQ(0, xv[0]) DOTQ(1, xv[1]) DOTQ(2, xv[2]) DOTQ(3, xv[3])
        DOTQ(4, xv[4]) DOTQ(5, xv[5]) DOTQ(6, xv[6]) DOTQ(7, xv[7])
        __syncthreads();                       // gp ready; all hs reads of this step done
        {
            int q0 = 2 * w, q1 = 2 * w + 1;
            float gi0 = gp[q0][j], gf0 = gp[q0][64 + j], gg0 = gp[q0][128 + j], go0 = gp[q0][192 + j];
            float gi1 = gp[q1][j], gf1 = gp[q1][64 + j], gg1 = gp[q1][128 + j], go1 = gp[q1][192 + j];
            c0 = sigm_f(gf0) * c0 + sigm_f(gi0) * tanh_f(gg0);
            c1 = sigm_f(gf1) * c1 + sigm_f(gi1) * tanh_f(gg1);
            h0 = sigm_f(go0) * tanh_f(c0);
            h1 = sigm_f(go1) * tanh_f(c1);
            hs[q0][j] = h0; hs[q1][j] = h1;
        }
        __syncthreads();                       // hs ready for next step
        #pragma unroll
        for (int q = 0; q < 8; ++q) xv[q] = xn8[q];
    }
    hlast[((size_t)blockIdx.x * 8 + 2 * w + 0) * 64 + j] = h0;
    hlast[((size_t)blockIdx.x * 8 + 2 * w + 1) * 64 + j] = h1;
}

// ---------------- FC head + softmax ----------------
__global__ __launch_bounds__(128) void head_kernel(const float* __restrict__ hl,
                                                   const float* __restrict__ w1, const float* __restrict__ b1,
                                                   const float* __restrict__ w2, const float* __restrict__ b2,
                                                   float* __restrict__ out) {
    __shared__ float hrow[64];
    __shared__ float a1[128];
    __shared__ float lg[3];
    int s = blockIdx.x, tid = threadIdx.x;
    if (tid < 64) hrow[tid] = hl[(size_t)s * 64 + tid];
    __syncthreads();
    {
        const float4* wr = (const float4*)(w1 + (size_t)tid * 64);
        const float4* hq = (const float4*)hrow;
        float4 acc = make_float4(0.f, 0.f, 0.f, 0.f);
        #pragma unroll
        for (int k = 0; k < 16; ++k) {
            float4 wv = wr[k]; float4 hv = hq[k];
            acc.x = fmaf(wv.x, hv.x, acc.x); acc.y = fmaf(wv.y, hv.y, acc.y);
            acc.z = fmaf(wv.z, hv.z, acc.z); acc.w = fmaf(wv.w, hv.w, acc.w);
        }
        a1[tid] = fmaxf((acc.x + acc.y) + (acc.z + acc.w) + b1[tid], 0.f);
    }
    __syncthreads();
    if (tid < 3) {
        const float4* wr = (const float4*)(w2 + (size_t)tid * 128);
        const float4* aq = (const float4*)a1;
        float4 acc = make_float4(0.f, 0.f, 0.f, 0.f);
        #pragma unroll
        for (int k = 0; k < 32; ++k) {
            float4 wv = wr[k]; float4 av = aq[k];
            acc.x = fmaf(wv.x, av.x, acc.x); acc.y = fmaf(wv.y, av.y, acc.y);
            acc.z = fmaf(wv.z, av.z, acc.z); acc.w = fmaf(wv.w, av.w, acc.w);
        }
        lg[tid] = (acc.x + acc.y) + (acc.z + acc.w) + b2[tid];
    }
    __syncthreads();
    if (tid == 0) {
        float m = fmaxf(lg[0], fmaxf(lg[1], lg[2]));
        float e0 = __expf(lg[0] - m), e1 = __expf(lg[1] - m), e2 = __expf(lg[2] - m);
        float inv = 1.f / (e0 + e1 + e2);
        out[(size_t)s * 3 + 0] = e0 * inv;
        out[(size_t)s * 3 + 1] = e1 * inv;
        out[(size_t)s * 3 + 2] = e2 * inv;
    }
}

extern "C" void kernel_launch(void* const* d_in, const int* in_sizes, int n_in,
                              void* d_out, int out_size, void* d_ws, size_t ws_size,
                              hipStream_t stream) {
    (void)in_sizes; (void)n_in; (void)out_size; (void)ws_size;
    const float* x        = (const float*)d_in[0];
    const float* ea       = (const float*)d_in[1];
    const float* conv1_w  = (const float*)d_in[2];
    const float* conv1_b  = (const float*)d_in[3];
    const float* conv2_w  = (const float*)d_in[4];
    const float* conv2_b  = (const float*)d_in[5];
    const float* w_ih     = (const float*)d_in[6];
    const float* w_hh     = (const float*)d_in[7];
    const float* b_ih     = (const float*)d_in[8];
    const float* b_hh     = (const float*)d_in[9];
    const float* fc1_w    = (const float*)d_in[10];
    const float* fc1_b    = (const float*)d_in[11];
    const float* fc2_w    = (const float*)d_in[12];
    const float* fc2_b    = (const float*)d_in[13];
    const int*   ei       = (const int*)d_in[14];
    float* out = (float*)d_out;

    float* W   = (float*)d_ws;
    float* a1  = W + OFF_A1;
    float* g1  = W + OFF_G1;
    float* xg  = W + OFF_XG;
    float* h2  = W + OFF_H2;
    float* g2  = W + OFF_G2;
    float* dis = W + OFF_DIS;
    float* hl  = W + OFF_HL;
    float* st  = W + OFF_ST;
    int*   roff    = (int*)(W + OFF_ROFF);
    int*   cursor  = (int*)(W + OFF_CUR);
    int2*  ent     = (int2*)(W + OFF_ENT);

    // init + normalization stats (normalization itself fused into gather-1)
    init_zero<<<NN / 256, 256, 0, stream>>>(cursor, st);
    col_sums<<<1024, 256, 0, stream>>>(x, st);
    finalize_stats<<<1, 64, 0, stream>>>(st);

    // CSR build (dest-sorted, packed); raw |ea| weights
    hist_acc<<<EE / 256, 256, 0, stream>>>(ei, cursor);
    scan_kernel<<<1, 1024, 0, stream>>>(cursor, roff, cursor);
    csr_fill<<<EE / 256, 256, 0, stream>>>(ei, ea, cursor, ent);
    row_norm<<<NN / 256, 256, 0, stream>>>(roff, ent, dis);

    // GCN layer 1, commuted: a1 = S·normalize(x) (64 cols), then g1 = a1 @ W1 (96 cols)
    gcn_gather<16, true><<<NN * 16 / 256, 256, 0, stream>>>(x, roff, ent, dis, st, a1);
    gemm_tiled<64, 96, 32, 192, false, false, false><<<NN / 32, 192, 0, stream>>>(
        a1, conv1_w, nullptr, nullptr, nullptr, g1, 96);

    // GCN layer 2: h2 = relu(g1+b1) @ W2 (64 cols), then g2 = S·h2
    gemm_tiled<96, 64, 64, 256, true, false, false><<<NN / 64, 256, 0, stream>>>(
        g1, conv2_w, conv1_b, nullptr, nullptr, h2, 64);
    gcn_gather<16, false><<<NN * 16 / 256, 256, 0, stream>>>(h2, roff, ent, dis, nullptr, g2);

    // LSTM input transform: xg = relu(g2+b2) @ w_ih^T + b_ih + b_hh (both col-halves in one launch)
    gemm_tiled<64, 128, 32, 256, true, true, true><<<dim3(NN / 32, 2), 256, 0, stream>>>(
        g2, w_ih, conv2_b, b_ih, b_hh, xg, 256);

    // LSTM recurrence (8 seqs/block)
    lstm_kernel<<<SS / 8, 256, 0, stream>>>(xg, w_hh, hl);

    // FC head + softmax
    head_kernel<<<SS, 128, 0, stream>>>(hl, fc1_w, fc1_b, fc2_w, fc2_b, out);
}

// Round 6
// 755.748 us; speedup vs baseline: 1.1126x; 1.1126x over previous
//
#include <hip/hip_runtime.h>
#include <hip/hip_bf16.h>

#define NN 102400      // B*T*NODES
#define DD 64
#define EE 1638400
#define L1C 96
#define L2C 64
#define TT 32
#define NODESC 400
#define BB 8
#define SS 3200        // B*NODES
#define G4 256         // 4*D

// ---------------- workspace layout (floats) ----------------
// big block [0, 26,214,400): a1 | g1 | ent(csr), later overwritten by xg
#define OFF_A1   ((size_t)6553600)    // NN*64
#define OFF_G1   ((size_t)13107200)   // NN*96 -> ends 22,937,600
#define OFF_ENT  ((size_t)22937600)   // EE int2 (2*EE floats) -> ends 26,214,400
#define OFF_XG   ((size_t)0)          // NN*256
#define OFF_H2   ((size_t)26214400)   // NN*64
#define OFF_G2   ((size_t)32768000)   // NN*64
#define OFF_DIS  ((size_t)39321600)   // NN
#define OFF_ROFF ((size_t)39424000)   // NN+1 ints (padded)
#define OFF_CUR  ((size_t)39526416)   // NN ints
#define OFF_HL   ((size_t)39628816)   // SS*64
#define OFF_ST   ((size_t)39833616)   // 256   -> total 39,833,872 floats = 159.3 MB

__device__ __forceinline__ void fma4(float4& a, float s, const float4& w) {
    a.x = fmaf(s, w.x, a.x); a.y = fmaf(s, w.y, a.y);
    a.z = fmaf(s, w.z, a.z); a.w = fmaf(s, w.w, a.w);
}
__device__ __forceinline__ float rcp_f(float x) { return __builtin_amdgcn_rcpf(x); }
__device__ __forceinline__ float sigm_f(float x) {
    x = fminf(fmaxf(x, -30.f), 30.f);
    return rcp_f(1.f + __expf(-x));
}
__device__ __forceinline__ float tanh_f(float x) {
    x = fminf(fmaxf(x, -15.f), 15.f);
    float e = __expf(2.f * x);
    return (e - 1.f) * rcp_f(e + 1.f);
}

// ---------------- init: zero cursor (hist) + stats ----------------
__global__ void init_zero(int* cursor, float* st) {
    int idx = blockIdx.x * 256 + threadIdx.x;
    if (idx < NN) cursor[idx] = 0;
    if (blockIdx.x == 0 && threadIdx.x < 128) st[threadIdx.x] = 0.f;
}

// ---------------- normalization stats ----------------
__global__ __launch_bounds__(256) void col_sums(const float* __restrict__ x, float* __restrict__ st) {
    int c = threadIdx.x & 63;
    size_t i = (size_t)blockIdx.x * 256 + threadIdx.x;
    size_t stride = (size_t)gridDim.x * 256;
    float s = 0.f, q = 0.f;
    for (size_t e = i; e < (size_t)NN * 64; e += stride) {
        float v = x[e]; s += v; q = fmaf(v, v, q);
    }
    __shared__ float ls[128];
    if (threadIdx.x < 128) ls[threadIdx.x] = 0.f;
    __syncthreads();
    atomicAdd(&ls[c], s); atomicAdd(&ls[64 + c], q);
    __syncthreads();
    if (threadIdx.x < 128) atomicAdd(&st[threadIdx.x], ls[threadIdx.x]);
}

__global__ void finalize_stats(float* st) {
    int c = threadIdx.x;
    if (c < 64) {
        float s = st[c], q = st[64 + c];
        float mean = s / (float)NN;
        float var = (q - s * s / (float)NN) / (float)(NN - 1);
        st[128 + c] = mean;
        st[192 + c] = rsqrtf(fmaxf(var, 1e-20f));
    }
}

// ---------------- CSR build (dest-sorted, packed 8B entries) ----------------
__global__ void hist_acc(const int* __restrict__ ei, int* __restrict__ cnt) {
    int e = blockIdx.x * 256 + threadIdx.x;
    atomicAdd(&cnt[ei[EE + e]], 1);
}

// single-block exclusive scan over NN counts; writes roff[0..NN] and cursor[0..NN-1]
__global__ __launch_bounds__(1024) void scan_kernel(int* __restrict__ cnt, int* __restrict__ roff, int* __restrict__ cursor) {
    __shared__ int part[1024];
    int tid = threadIdx.x;
    int base = tid * (NN / 1024);
    int s = 0;
    for (int i = 0; i < NN / 1024; ++i) s += cnt[base + i];
    part[tid] = s;
    __syncthreads();
    for (int d = 1; d < 1024; d <<= 1) {
        int v = (tid >= d) ? part[tid - d] : 0;
        __syncthreads();
        part[tid] += v;
        __syncthreads();
    }
    int run = part[tid] - s;     // exclusive prefix of this thread's range
    for (int i = 0; i < NN / 1024; ++i) {
        int c = cnt[base + i];
        roff[base + i] = run;
        cursor[base + i] = run;
        run += c;
    }
    if (tid == 1023) roff[NN] = run;
}

__global__ void csr_fill(const int* __restrict__ ei, const float* __restrict__ ea,
                         int* __restrict__ cursor, int2* __restrict__ ent) {
    int e = blockIdx.x * 256 + threadIdx.x;
    int d = ei[EE + e];
    int pos = atomicAdd(&cursor[d], 1);
    ent[pos] = make_int2(ei[e], __float_as_int(fabsf(ea[2 * (size_t)e])));
}

// deg[n] = 1 + sum of raw weights in row n (self-loop weight 1); dis = rsqrt(deg)
__global__ void row_norm(const int* __restrict__ roff, const int2* __restrict__ ent, float* __restrict__ dis) {
    int n = blockIdx.x * 256 + threadIdx.x;
    int e0 = roff[n], e1 = roff[n + 1];
    float deg = 1.f;
    for (int e = e0; e < e1; ++e) deg += __int_as_float(ent[e].y);
    dis[n] = rsqrtf(deg);
}

// ---------------- tiled f32 GEMM ----------------
template<int K, int NC, int MB, int THREADS, bool PRELU, bool TRANSW, bool XGOUT>
__global__ __launch_bounds__(THREADS) void gemm_tiled(
    const float* __restrict__ A, const float* __restrict__ Wm,
    const float* __restrict__ bin, const float* __restrict__ bo1, const float* __restrict__ bo2,
    float* __restrict__ Cm, int ldC)
{
    __shared__ float As[MB * K];
    __shared__ float Ws[K * NC];
    const int cb0 = TRANSW ? ((int)blockIdx.y * NC) : 0;   // xg column-half select

    if (!TRANSW) {
        for (int i = threadIdx.x; i < K * NC / 4; i += THREADS)
            ((float4*)Ws)[i] = ((const float4*)Wm)[i];
    } else {
        for (int i = threadIdx.x; i < NC * (K / 4); i += THREADS) {
            int g = i / (K / 4); int d = (i % (K / 4)) * 4;
            float4 v = *(const float4*)(Wm + (size_t)(cb0 + g) * K + d);
            Ws[(d + 0) * NC + g] = v.x; Ws[(d + 1) * NC + g] = v.y;
            Ws[(d + 2) * NC + g] = v.z; Ws[(d + 3) * NC + g] = v.w;
        }
    }
    size_t row0 = (size_t)blockIdx.x * MB;
    for (int i = threadIdx.x; i < MB * (K / 4); i += THREADS) {
        int r = i / (K / 4); int c = (i % (K / 4)) * 4;
        float4 a = *(const float4*)(A + (row0 + r) * K + c);
        if (PRELU) {
            a.x = fmaxf(a.x + bin[c + 0], 0.f); a.y = fmaxf(a.y + bin[c + 1], 0.f);
            a.z = fmaxf(a.z + bin[c + 2], 0.f); a.w = fmaxf(a.w + bin[c + 3], 0.f);
        }
        ((float4*)As)[i] = a;
    }
    __syncthreads();

    constexpr int NCT = NC / 4;
    int tc = threadIdx.x % NCT;
    int tr = threadIdx.x / NCT;
    int r = tr * 4;
    float4 acc[4];
    acc[0] = acc[1] = acc[2] = acc[3] = make_float4(0.f, 0.f, 0.f, 0.f);

    #pragma unroll 8
    for (int d4 = 0; d4 < K / 4; ++d4) {
        float4 w0 = ((const float4*)Ws)[(4 * d4 + 0) * NCT + tc];
        float4 w1 = ((const float4*)Ws)[(4 * d4 + 1) * NCT + tc];
        float4 w2 = ((const float4*)Ws)[(4 * d4 + 2) * NCT + tc];
        float4 w3 = ((const float4*)Ws)[(4 * d4 + 3) * NCT + tc];
        #pragma unroll
        for (int i = 0; i < 4; ++i) {
            float4 av = ((const float4*)As)[(r + i) * (K / 4) + d4];
            fma4(acc[i], av.x, w0); fma4(acc[i], av.y, w1);
            fma4(acc[i], av.z, w2); fma4(acc[i], av.w, w3);
        }
    }

    if (!XGOUT) {
        #pragma unroll
        for (int i = 0; i < 4; ++i) {
            size_t row = row0 + r + i;
            *(float4*)(Cm + row * ldC + tc * 4) = acc[i];
        }
    } else {
        int cb = cb0 + tc * 4;
        float4 bs;
        bs.x = bo1[cb + 0] + bo2[cb + 0]; bs.y = bo1[cb + 1] + bo2[cb + 1];
        bs.z = bo1[cb + 2] + bo2[cb + 2]; bs.w = bo1[cb + 3] + bo2[cb + 3];
        #pragma unroll
        for (int i = 0; i < 4; ++i) {
            int n = (int)row0 + r + i;                      // n = b*T*NODES + t*NODES + node
            int b_ = n / (TT * NODESC);
            int rem = n - b_ * (TT * NODESC);
            int t = rem / NODESC;
            int node = rem - t * NODESC;
            int orow = (b_ * NODESC + node) * TT + t;       // seq-major, time inner
            float4 o = acc[i];
            o.x += bs.x; o.y += bs.y; o.z += bs.z; o.w += bs.w;
            *(float4*)(Cm + (size_t)orow * ldC + cb) = o;
        }
    }
}

// ---------------- GCN aggregation: gather over packed CSR, dis folded in ----------------
// g[n] = dis[n] * ( dis[n]*h[n] + sum_e w_e*dis[src_e]*h[src_e] )
// NORM variant normalizes h rows on the fly from raw x + column stats (saves xn round-trip).
template<int C4, bool NORM>
__global__ __launch_bounds__(256) void gcn_gather(const float* __restrict__ h, const int* __restrict__ roff,
                                                  const int2* __restrict__ ent, const float* __restrict__ dis,
                                                  const float* __restrict__ st, float* __restrict__ g) {
    unsigned int idx = blockIdx.x * 256 + threadIdx.x;
    unsigned int n = idx / C4, q = idx % C4;
    float4 mean4, istd4;
    if (NORM) {
        mean4 = ((const float4*)(st + 128))[q];
        istd4 = ((const float4*)(st + 192))[q];
    }
    float dn = dis[n];
    float4 acc = ((const float4*)h)[(size_t)n * C4 + q];
    if (NORM) {
        acc.x = (acc.x - mean4.x) * istd4.x; acc.y = (acc.y - mean4.y) * istd4.y;
        acc.z = (acc.z - mean4.z) * istd4.z; acc.w = (acc.w - mean4.w) * istd4.w;
    }
    acc.x *= dn; acc.y *= dn; acc.z *= dn; acc.w *= dn;
    int e0 = roff[n], e1 = roff[n + 1];
    for (int e = e0; e < e1; ++e) {
        int2 en = ent[e];
        float w = __int_as_float(en.y) * dis[en.x];
        float4 v = ((const float4*)h)[(size_t)en.x * C4 + q];
        if (NORM) {
            v.x = (v.x - mean4.x) * istd4.x; v.y = (v.y - mean4.y) * istd4.y;
            v.z = (v.z - mean4.z) * istd4.z; v.w = (v.w - mean4.w) * istd4.w;
        }
        fma4(acc, w, v);
    }
    acc.x *= dn; acc.y *= dn; acc.z *= dn; acc.w *= dn;
    ((float4*)g)[(size_t)n * C4 + q] = acc;
}

// ---------------- LSTM (recurrent part; xg precomputed) ----------------
// 512 threads = 8 waves; 8 seqs/block (grid 400).
// Dot phase: thread pair (2r, 2r+1) owns gate-row r; each holds HALF a w_hh row
// (8 float4 = 32 VGPRs — small enough that the allocator keeps it resident,
// unlike the 64-VGPR/thread variants which got demoted; see R4/R5 post-mortems).
// Partials combined with one __shfl_xor. Activation phase: thread tid owns
// (seq=tid>>6, unit=tid&63); it adds the xg gate inputs (4 scalar loads/t,
// software-pipelined one step ahead) and updates c/h in registers.
#define HSTEP(i, wv) { float4 hv = hq[i]; \
    acc.x = fmaf(hv.x, wv.x, acc.x); acc.y = fmaf(hv.y, wv.y, acc.y); \
    acc.z = fmaf(hv.z, wv.z, acc.z); acc.w = fmaf(hv.w, wv.w, acc.w); }

__global__ __launch_bounds__(512, 1) void lstm_kernel(const float* __restrict__ xg, const float* __restrict__ whh,
                                                      float* __restrict__ hlast) {
    __shared__ float hs[8][64];
    __shared__ float gp[8][256];
    const int tid = threadIdx.x;          // 0..511
    const int row = tid >> 1;             // gate row 0..255
    const int half = tid & 1;             // which 32-wide k-half
    const int qa = tid >> 6;              // activation: seq 0..7
    const int ja = tid & 63;              // activation: hidden unit
    const float4* wr = (const float4*)(whh + (size_t)row * 64 + half * 32);
    const float4 w0 = wr[0], w1 = wr[1], w2 = wr[2], w3 = wr[3];
    const float4 w4 = wr[4], w5 = wr[5], w6 = wr[6], w7 = wr[7];
    float c_reg = 0.f, hn = 0.f;
    ((float*)hs)[tid] = 0.f;              // 512 floats == hs exactly
    // activation-side xg pointers: gate g value for (qa, t, ja) at
    // xg[(qa*TT + t)*256 + g*64 + ja] relative to block base
    const float* xa = xg + (size_t)blockIdx.x * 8 * TT * G4 + (size_t)qa * TT * G4 + ja;
    float xi = xa[0], xf = xa[64], xgv = xa[128], xo = xa[192];
    __syncthreads();
    for (int t = 0; t < TT; ++t) {
        // prefetch next step's gate inputs (consumed after the barrier next iter)
        const int tn = (t + 1 < TT) ? t + 1 : t;
        const float* xan = xa + tn * G4;
        float ni = xan[0], nf = xan[64], ng = xan[128], no = xan[192];
        #pragma unroll
        for (int q = 0; q < 8; ++q) {
            const float4* hq = (const float4*)hs[q] + half * 8;
            float4 acc = make_float4(0.f, 0.f, 0.f, 0.f);
            HSTEP(0, w0) HSTEP(1, w1) HSTEP(2, w2) HSTEP(3, w3)
            HSTEP(4, w4) HSTEP(5, w5) HSTEP(6, w6) HSTEP(7, w7)
            float p = (acc.x + acc.y) + (acc.z + acc.w);
            p += __shfl_xor(p, 1);
            if (half == 0) gp[q][row] = p;
        }
        __syncthreads();                  // gp ready; hs reads done
        {
            float gi = gp[qa][ja]       + xi;
            float gf = gp[qa][64 + ja]  + xf;
            float gg = gp[qa][128 + ja] + xgv;
            float go = gp[qa][192 + ja] + xo;
            c_reg = sigm_f(gf) * c_reg + sigm_f(gi) * tanh_f(gg);
            hn = sigm_f(go) * tanh_f(c_reg);
            hs[qa][ja] = hn;
        }
        __syncthreads();                  // hs ready for next step
        xi = ni; xf = nf; xgv = ng; xo = no;
    }
    hlast[((size_t)blockIdx.x * 8 + qa) * 64 + ja] = hn;
}

// ---------------- FC head + softmax ----------------
__global__ __launch_bounds__(128) void head_kernel(const float* __restrict__ hl,
                                                   const float* __restrict__ w1, const float* __restrict__ b1,
                                                   const float* __restrict__ w2, const float* __restrict__ b2,
                                                   float* __restrict__ out) {
    __shared__ float hrow[64];
    __shared__ float a1[128];
    __shared__ float lg[3];
    int s = blockIdx.x, tid = threadIdx.x;
    if (tid < 64) hrow[tid] = hl[(size_t)s * 64 + tid];
    __syncthreads();
    {
        const float4* wr = (const float4*)(w1 + (size_t)tid * 64);
        const float4* hq = (const float4*)hrow;
        float4 acc = make_float4(0.f, 0.f, 0.f, 0.f);
        #pragma unroll
        for (int k = 0; k < 16; ++k) {
            float4 wv = wr[k]; float4 hv = hq[k];
            acc.x = fmaf(wv.x, hv.x, acc.x); acc.y = fmaf(wv.y, hv.y, acc.y);
            acc.z = fmaf(wv.z, hv.z, acc.z); acc.w = fmaf(wv.w, hv.w, acc.w);
        }
        a1[tid] = fmaxf((acc.x + acc.y) + (acc.z + acc.w) + b1[tid], 0.f);
    }
    __syncthreads();
    if (tid < 3) {
        const float4* wr = (const float4*)(w2 + (size_t)tid * 128);
        const float4* aq = (const float4*)a1;
        float4 acc = make_float4(0.f, 0.f, 0.f, 0.f);
        #pragma unroll
        for (int k = 0; k < 32; ++k) {
            float4 wv = wr[k]; float4 av = aq[k];
            acc.x = fmaf(wv.x, av.x, acc.x); acc.y = fmaf(wv.y, av.y, acc.y);
            acc.z = fmaf(wv.z, av.z, acc.z); acc.w = fmaf(wv.w, av.w, acc.w);
        }
        lg[tid] = (acc.x + acc.y) + (acc.z + acc.w) + b2[tid];
    }
    __syncthreads();
    if (tid == 0) {
        float m = fmaxf(lg[0], fmaxf(lg[1], lg[2]));
        float e0 = __expf(lg[0] - m), e1 = __expf(lg[1] - m), e2 = __expf(lg[2] - m);
        float inv = 1.f / (e0 + e1 + e2);
        out[(size_t)s * 3 + 0] = e0 * inv;
        out[(size_t)s * 3 + 1] = e1 * inv;
        out[(size_t)s * 3 + 2] = e2 * inv;
    }
}

extern "C" void kernel_launch(void* const* d_in, const int* in_sizes, int n_in,
                              void* d_out, int out_size, void* d_ws, size_t ws_size,
                              hipStream_t stream) {
    (void)in_sizes; (void)n_in; (void)out_size; (void)ws_size;
    const float* x        = (const float*)d_in[0];
    const float* ea       = (const float*)d_in[1];
    const float* conv1_w  = (const float*)d_in[2];
    const float* conv1_b  = (const float*)d_in[3];
    const float* conv2_w  = (const float*)d_in[4];
    const float* conv2_b  = (const float*)d_in[5];
    const float* w_ih     = (const float*)d_in[6];
    const float* w_hh     = (const float*)d_in[7];
    const float* b_ih     = (const float*)d_in[8];
    const float* b_hh     = (const float*)d_in[9];
    const float* fc1_w    = (const float*)d_in[10];
    const float* fc1_b    = (const float*)d_in[11];
    const float* fc2_w    = (const float*)d_in[12];
    const float* fc2_b    = (const float*)d_in[13];
    const int*   ei       = (const int*)d_in[14];
    float* out = (float*)d_out;

    float* W   = (float*)d_ws;
    float* a1  = W + OFF_A1;
    float* g1  = W + OFF_G1;
    float* xg  = W + OFF_XG;
    float* h2  = W + OFF_H2;
    float* g2  = W + OFF_G2;
    float* dis = W + OFF_DIS;
    float* hl  = W + OFF_HL;
    float* st  = W + OFF_ST;
    int*   roff    = (int*)(W + OFF_ROFF);
    int*   cursor  = (int*)(W + OFF_CUR);
    int2*  ent     = (int2*)(W + OFF_ENT);

    // init + normalization stats (normalization itself fused into gather-1)
    init_zero<<<NN / 256, 256, 0, stream>>>(cursor, st);
    col_sums<<<1024, 256, 0, stream>>>(x, st);
    finalize_stats<<<1, 64, 0, stream>>>(st);

    // CSR build (dest-sorted, packed); raw |ea| weights
    hist_acc<<<EE / 256, 256, 0, stream>>>(ei, cursor);
    scan_kernel<<<1, 1024, 0, stream>>>(cursor, roff, cursor);
    csr_fill<<<EE / 256, 256, 0, stream>>>(ei, ea, cursor, ent);
    row_norm<<<NN / 256, 256, 0, stream>>>(roff, ent, dis);

    // GCN layer 1, commuted: a1 = S·normalize(x) (64 cols), then g1 = a1 @ W1 (96 cols)
    gcn_gather<16, true><<<NN * 16 / 256, 256, 0, stream>>>(x, roff, ent, dis, st, a1);
    gemm_tiled<64, 96, 32, 192, false, false, false><<<NN / 32, 192, 0, stream>>>(
        a1, conv1_w, nullptr, nullptr, nullptr, g1, 96);

    // GCN layer 2: h2 = relu(g1+b1) @ W2 (64 cols), then g2 = S·h2
    gemm_tiled<96, 64, 64, 256, true, false, false><<<NN / 64, 256, 0, stream>>>(
        g1, conv2_w, conv1_b, nullptr, nullptr, h2, 64);
    gcn_gather<16, false><<<NN * 16 / 256, 256, 0, stream>>>(h2, roff, ent, dis, nullptr, g2);

    // LSTM input transform: xg = relu(g2+b2) @ w_ih^T + b_ih + b_hh (both col-halves in one launch)
    gemm_tiled<64, 128, 32, 256, true, true, true><<<dim3(NN / 32, 2), 256, 0, stream>>>(
        g2, w_ih, conv2_b, b_ih, b_hh, xg, 256);

    // LSTM recurrence (8 seqs/block, 512 threads: dot pairs + activation threads)
    lstm_kernel<<<SS / 8, 512, 0, stream>>>(xg, w_hh, hl);

    // FC head + softmax
    head_kernel<<<SS, 128, 0, stream>>>(hl, fc1_w, fc1_b, fc2_w, fc2_b, out);
}

// Round 7
// 610.894 us; speedup vs baseline: 1.3764x; 1.2371x over previous
//
#include <hip/hip_runtime.h>
#include <hip/hip_bf16.h>

#define NN 102400      // B*T*NODES
#define DD 64
#define EE 1638400
#define L1C 96
#define L2C 64
#define TT 32
#define NODESC 400
#define BB 8
#define SS 3200        // B*NODES
#define G4 256         // 4*D

#define NBUK 400       // coarse buckets (node >> 8), NN = 400*256 exactly
#define BCAP 5120      // slots per bucket (mean 4096, sd 64 -> +16 sigma)
#define PCHUNK 8192
#define NPART (EE / PCHUNK)   // 200

// ---------------- workspace layout (floats) ----------------
// [0, 26,214,400): ent | a1 | g1  -> all dead before xg overwrites the region
#define OFF_ENT  ((size_t)0)          // NBUK*BCAP int2 = 4,096,000 floats
#define OFF_A1   ((size_t)4096000)    // NN*64 -> ends 10,649,600
#define OFF_G1   ((size_t)10649600)   // NN*96 -> ends 20,480,000
#define OFF_XG   ((size_t)0)          // NN*256 = 26,214,400
#define OFF_ENT2 ((size_t)26214400)   // staging, 4,096,000 (dead before h2 written)
#define OFF_H2   ((size_t)26214400)   // NN*64 -> ends 32,768,000
#define OFF_G2   ((size_t)32768000)   // NN*64 -> ends 39,321,600
#define OFF_GCUR ((size_t)39321600)   // 400 cursors padded x16 ints = 6400
#define OFF_DIS  ((size_t)39328000)   // NN -> ends 39,430,400
#define OFF_RNG  ((size_t)39430400)   // NN int2 -> ends 39,635,200
#define OFF_HL   ((size_t)39635200)   // SS*64 -> ends 39,840,000
#define OFF_ST   ((size_t)39840000)   // 256 -> total 39,840,256 floats (159.4 MB)

__device__ __forceinline__ void fma4(float4& a, float s, const float4& w) {
    a.x = fmaf(s, w.x, a.x); a.y = fmaf(s, w.y, a.y);
    a.z = fmaf(s, w.z, a.z); a.w = fmaf(s, w.w, a.w);
}
__device__ __forceinline__ float rcp_f(float x) { return __builtin_amdgcn_rcpf(x); }
__device__ __forceinline__ float sigm_f(float x) {
    x = fminf(fmaxf(x, -30.f), 30.f);
    return rcp_f(1.f + __expf(-x));
}
__device__ __forceinline__ float tanh_f(float x) {
    x = fminf(fmaxf(x, -15.f), 15.f);
    float e = __expf(2.f * x);
    return (e - 1.f) * rcp_f(e + 1.f);
}

// ---------------- init: zero bucket cursors + stats ----------------
__global__ void init_zero(int* gcur, float* st) {
    int idx = blockIdx.x * 256 + threadIdx.x;
    if (idx < NBUK * 16) gcur[idx] = 0;
    if (blockIdx.x == 0 && threadIdx.x < 128) st[threadIdx.x] = 0.f;
}

// ---------------- normalization stats ----------------
__global__ __launch_bounds__(256) void col_sums(const float* __restrict__ x, float* __restrict__ st) {
    int c = threadIdx.x & 63;
    size_t i = (size_t)blockIdx.x * 256 + threadIdx.x;
    size_t stride = (size_t)gridDim.x * 256;
    float s = 0.f, q = 0.f;
    for (size_t e = i; e < (size_t)NN * 64; e += stride) {
        float v = x[e]; s += v; q = fmaf(v, v, q);
    }
    __shared__ float ls[128];
    if (threadIdx.x < 128) ls[threadIdx.x] = 0.f;
    __syncthreads();
    atomicAdd(&ls[c], s); atomicAdd(&ls[64 + c], q);
    __syncthreads();
    if (threadIdx.x < 128) atomicAdd(&st[threadIdx.x], ls[threadIdx.x]);
}

__global__ void finalize_stats(float* st) {
    int c = threadIdx.x;
    if (c < 64) {
        float s = st[c], q = st[64 + c];
        float mean = s / (float)NN;
        float var = (q - s * s / (float)NN) / (float)(NN - 1);
        st[128 + c] = mean;
        st[192 + c] = rsqrtf(fmaxf(var, 1e-20f));
    }
}

// ---------------- pass 1: coarse bucket partition (contiguous block-local runs) ----------------
// Entry staging format: meta = src | (dst&255)<<24 (src < 2^17), w = |ea| bits.
__global__ __launch_bounds__(256) void part_kernel(const int* __restrict__ ei, const float* __restrict__ ea,
                                                   int* __restrict__ gcur, int2* __restrict__ ent2) {
    __shared__ int lhist[NBUK];
    __shared__ int lbase[NBUK];
    const int tid = threadIdx.x;
    const int e0 = blockIdx.x * PCHUNK;
    for (int i = tid; i < NBUK; i += 256) lhist[i] = 0;
    __syncthreads();
    #pragma unroll 4
    for (int i = 0; i < PCHUNK / 256; ++i) {
        int d = ei[EE + e0 + i * 256 + tid];
        atomicAdd(&lhist[d >> 8], 1);
    }
    __syncthreads();
    // reserve one contiguous range per bucket (gcur padded: 1 counter / 64B line)
    for (int i = tid; i < NBUK; i += 256) {
        lbase[i] = atomicAdd(&gcur[i * 16], lhist[i]);
        lhist[i] = 0;
    }
    __syncthreads();
    for (int i = 0; i < PCHUNK / 256; ++i) {
        int e = e0 + i * 256 + tid;
        int d = ei[EE + e];
        int s = ei[e];
        float w = fabsf(ea[2 * (size_t)e]);
        int b = d >> 8;
        int local = atomicAdd(&lhist[b], 1);
        int pos = lbase[b] + local;
        if (pos < BCAP)
            ent2[(size_t)b * BCAP + pos] = make_int2(s | ((d & 255) << 24), __float_as_int(w));
    }
}

// ---------------- pass 2: per-bucket counting sort in LDS + rng + dis ----------------
__global__ __launch_bounds__(256) void bucket_csr(const int2* __restrict__ ent2, const int* __restrict__ gcur,
                                                  int2* __restrict__ ent, int2* __restrict__ rng,
                                                  float* __restrict__ dis) {
    __shared__ int nhist[256];
    __shared__ int scn[256];
    __shared__ float wsum[256];
    __shared__ int pcur[256];
    const int tid = threadIdx.x;
    const int b = blockIdx.x;
    const int base = b * BCAP;
    int cnt = gcur[b * 16];
    if (cnt > BCAP) cnt = BCAP;
    nhist[tid] = 0;
    wsum[tid] = 0.f;
    __syncthreads();
    for (int e = tid; e < cnt; e += 256) {
        int2 en = ent2[base + e];
        int dl = ((unsigned)en.x) >> 24;
        atomicAdd(&nhist[dl], 1);
        atomicAdd(&wsum[dl], __int_as_float(en.y));
    }
    __syncthreads();
    int c = nhist[tid];
    scn[tid] = c;
    __syncthreads();
    for (int d = 1; d < 256; d <<= 1) {
        int t = (tid >= d) ? scn[tid - d] : 0;
        __syncthreads();
        scn[tid] += t;
        __syncthreads();
    }
    int ps = scn[tid] - c;                       // exclusive prefix within bucket
    rng[b * 256 + tid] = make_int2(base + ps, base + ps + c);
    dis[b * 256 + tid] = rsqrtf(1.f + wsum[tid]); // self-loop weight 1 folded in
    pcur[tid] = ps;
    __syncthreads();
    for (int e = tid; e < cnt; e += 256) {
        int2 en = ent2[base + e];
        int dl = ((unsigned)en.x) >> 24;
        int local = atomicAdd(&pcur[dl], 1);
        ent[base + local] = make_int2(en.x & 0xFFFFFF, en.y);
    }
}

// ---------------- tiled f32 GEMM ----------------
template<int K, int NC, int MB, int THREADS, bool PRELU, bool TRANSW, bool XGOUT>
__global__ __launch_bounds__(THREADS) void gemm_tiled(
    const float* __restrict__ A, const float* __restrict__ Wm,
    const float* __restrict__ bin, const float* __restrict__ bo1, const float* __restrict__ bo2,
    float* __restrict__ Cm, int ldC)
{
    __shared__ float As[MB * K];
    __shared__ float Ws[K * NC];
    const int cb0 = TRANSW ? ((int)blockIdx.y * NC) : 0;   // xg column-half select

    if (!TRANSW) {
        for (int i = threadIdx.x; i < K * NC / 4; i += THREADS)
            ((float4*)Ws)[i] = ((const float4*)Wm)[i];
    } else {
        for (int i = threadIdx.x; i < NC * (K / 4); i += THREADS) {
            int g = i / (K / 4); int d = (i % (K / 4)) * 4;
            float4 v = *(const float4*)(Wm + (size_t)(cb0 + g) * K + d);
            Ws[(d + 0) * NC + g] = v.x; Ws[(d + 1) * NC + g] = v.y;
            Ws[(d + 2) * NC + g] = v.z; Ws[(d + 3) * NC + g] = v.w;
        }
    }
    size_t row0 = (size_t)blockIdx.x * MB;
    for (int i = threadIdx.x; i < MB * (K / 4); i += THREADS) {
        int r = i / (K / 4); int c = (i % (K / 4)) * 4;
        float4 a = *(const float4*)(A + (row0 + r) * K + c);
        if (PRELU) {
            a.x = fmaxf(a.x + bin[c + 0], 0.f); a.y = fmaxf(a.y + bin[c + 1], 0.f);
            a.z = fmaxf(a.z + bin[c + 2], 0.f); a.w = fmaxf(a.w + bin[c + 3], 0.f);
        }
        ((float4*)As)[i] = a;
    }
    __syncthreads();

    constexpr int NCT = NC / 4;
    int tc = threadIdx.x % NCT;
    int tr = threadIdx.x / NCT;
    int r = tr * 4;
    float4 acc[4];
    acc[0] = acc[1] = acc[2] = acc[3] = make_float4(0.f, 0.f, 0.f, 0.f);

    #pragma unroll 8
    for (int d4 = 0; d4 < K / 4; ++d4) {
        float4 w0 = ((const float4*)Ws)[(4 * d4 + 0) * NCT + tc];
        float4 w1 = ((const float4*)Ws)[(4 * d4 + 1) * NCT + tc];
        float4 w2 = ((const float4*)Ws)[(4 * d4 + 2) * NCT + tc];
        float4 w3 = ((const float4*)Ws)[(4 * d4 + 3) * NCT + tc];
        #pragma unroll
        for (int i = 0; i < 4; ++i) {
            float4 av = ((const float4*)As)[(r + i) * (K / 4) + d4];
            fma4(acc[i], av.x, w0); fma4(acc[i], av.y, w1);
            fma4(acc[i], av.z, w2); fma4(acc[i], av.w, w3);
        }
    }

    if (!XGOUT) {
        #pragma unroll
        for (int i = 0; i < 4; ++i) {
            size_t row = row0 + r + i;
            *(float4*)(Cm + row * ldC + tc * 4) = acc[i];
        }
    } else {
        int cb = cb0 + tc * 4;
        float4 bs;
        bs.x = bo1[cb + 0] + bo2[cb + 0]; bs.y = bo1[cb + 1] + bo2[cb + 1];
        bs.z = bo1[cb + 2] + bo2[cb + 2]; bs.w = bo1[cb + 3] + bo2[cb + 3];
        #pragma unroll
        for (int i = 0; i < 4; ++i) {
            int n = (int)row0 + r + i;                      // n = b*T*NODES + t*NODES + node
            int b_ = n / (TT * NODESC);
            int rem = n - b_ * (TT * NODESC);
            int t = rem / NODESC;
            int node = rem - t * NODESC;
            int orow = (b_ * NODESC + node) * TT + t;       // seq-major, time inner
            float4 o = acc[i];
            o.x += bs.x; o.y += bs.y; o.z += bs.z; o.w += bs.w;
            *(float4*)(Cm + (size_t)orow * ldC + cb) = o;
        }
    }
}

// ---------------- GCN aggregation: gather over packed CSR (rng int2 ranges) ----------------
// g[n] = dis[n] * ( dis[n]*h[n] + sum_e w_e*dis[src_e]*h[src_e] )
template<int C4, bool NORM>
__global__ __launch_bounds__(256) void gcn_gather(const float* __restrict__ h, const int2* __restrict__ rng,
                                                  const int2* __restrict__ ent, const float* __restrict__ dis,
                                                  const float* __restrict__ st, float* __restrict__ g) {
    unsigned int idx = blockIdx.x * 256 + threadIdx.x;
    unsigned int n = idx / C4, q = idx % C4;
    float4 mean4, istd4;
    if (NORM) {
        mean4 = ((const float4*)(st + 128))[q];
        istd4 = ((const float4*)(st + 192))[q];
    }
    float dn = dis[n];
    float4 acc = ((const float4*)h)[(size_t)n * C4 + q];
    if (NORM) {
        acc.x = (acc.x - mean4.x) * istd4.x; acc.y = (acc.y - mean4.y) * istd4.y;
        acc.z = (acc.z - mean4.z) * istd4.z; acc.w = (acc.w - mean4.w) * istd4.w;
    }
    acc.x *= dn; acc.y *= dn; acc.z *= dn; acc.w *= dn;
    int2 r = rng[n];
    for (int e = r.x; e < r.y; ++e) {
        int2 en = ent[e];
        float w = __int_as_float(en.y) * dis[en.x];
        float4 v = ((const float4*)h)[(size_t)en.x * C4 + q];
        if (NORM) {
            v.x = (v.x - mean4.x) * istd4.x; v.y = (v.y - mean4.y) * istd4.y;
            v.z = (v.z - mean4.z) * istd4.z; v.w = (v.w - mean4.w) * istd4.w;
        }
        fma4(acc, w, v);
    }
    acc.x *= dn; acc.y *= dn; acc.z *= dn; acc.w *= dn;
    ((float4*)g)[(size_t)n * C4 + q] = acc;
}

// ---------------- LSTM (recurrent part; xg precomputed) ----------------
// 512 threads = 8 waves; 8 seqs/block (grid 400). Thread pair (2r,2r+1) owns
// gate-row r, each holding HALF a w_hh row (32 VGPRs -- stays resident, see R4-R6
// post-mortems: per-thread loop-live state must be <=32 VGPRs on this compiler).
#define HSTEP(i, wv) { float4 hv = hq[i]; \
    acc.x = fmaf(hv.x, wv.x, acc.x); acc.y = fmaf(hv.y, wv.y, acc.y); \
    acc.z = fmaf(hv.z, wv.z, acc.z); acc.w = fmaf(hv.w, wv.w, acc.w); }

__global__ __launch_bounds__(512, 1) void lstm_kernel(const float* __restrict__ xg, const float* __restrict__ whh,
                                                      float* __restrict__ hlast) {
    __shared__ float hs[8][64];
    __shared__ float gp[8][256];
    const int tid = threadIdx.x;          // 0..511
    const int row = tid >> 1;             // gate row 0..255
    const int half = tid & 1;             // which 32-wide k-half
    const int qa = tid >> 6;              // activation: seq 0..7
    const int ja = tid & 63;              // activation: hidden unit
    const float4* wr = (const float4*)(whh + (size_t)row * 64 + half * 32);
    const float4 w0 = wr[0], w1 = wr[1], w2 = wr[2], w3 = wr[3];
    const float4 w4 = wr[4], w5 = wr[5], w6 = wr[6], w7 = wr[7];
    float c_reg = 0.f, hn = 0.f;
    ((float*)hs)[tid] = 0.f;              // 512 floats == hs exactly
    const float* xa = xg + (size_t)blockIdx.x * 8 * TT * G4 + (size_t)qa * TT * G4 + ja;
    float xi = xa[0], xf = xa[64], xgv = xa[128], xo = xa[192];
    __syncthreads();
    for (int t = 0; t < TT; ++t) {
        const int tn = (t + 1 < TT) ? t + 1 : t;
        const float* xan = xa + tn * G4;
        float ni = xan[0], nf = xan[64], ng = xan[128], no = xan[192];
        #pragma unroll
        for (int q = 0; q < 8; ++q) {
            const float4* hq = (const float4*)hs[q] + half * 8;
            float4 acc = make_float4(0.f, 0.f, 0.f, 0.f);
            HSTEP(0, w0) HSTEP(1, w1) HSTEP(2, w2) HSTEP(3, w3)
            HSTEP(4, w4) HSTEP(5, w5) HSTEP(6, w6) HSTEP(7, w7)
            float p = (acc.x + acc.y) + (acc.z + acc.w);
            p += __shfl_xor(p, 1);
            if (half == 0) gp[q][row] = p;
        }
        __syncthreads();                  // gp ready; hs reads done
        {
            float gi = gp[qa][ja]       + xi;
            float gf = gp[qa][64 + ja]  + xf;
            float gg = gp[qa][128 + ja] + xgv;
            float go = gp[qa][192 + ja] + xo;
            c_reg = sigm_f(gf) * c_reg + sigm_f(gi) * tanh_f(gg);
            hn = sigm_f(go) * tanh_f(c_reg);
            hs[qa][ja] = hn;
        }
        __syncthreads();                  // hs ready for next step
        xi = ni; xf = nf; xgv = ng; xo = no;
    }
    hlast[((size_t)blockIdx.x * 8 + qa) * 64 + ja] = hn;
}

// ---------------- FC head + softmax ----------------
__global__ __launch_bounds__(128) void head_kernel(const float* __restrict__ hl,
                                                   const float* __restrict__ w1, const float* __restrict__ b1,
                                                   const float* __restrict__ w2, const float* __restrict__ b2,
                                                   float* __restrict__ out) {
    __shared__ float hrow[64];
    __shared__ float a1[128];
    __shared__ float lg[3];
    int s = blockIdx.x, tid = threadIdx.x;
    if (tid < 64) hrow[tid] = hl[(size_t)s * 64 + tid];
    __syncthreads();
    {
        const float4* wr = (const float4*)(w1 + (size_t)tid * 64);
        const float4* hq = (const float4*)hrow;
        float4 acc = make_float4(0.f, 0.f, 0.f, 0.f);
        #pragma unroll
        for (int k = 0; k < 16; ++k) {
            float4 wv = wr[k]; float4 hv = hq[k];
            acc.x = fmaf(wv.x, hv.x, acc.x); acc.y = fmaf(wv.y, hv.y, acc.y);
            acc.z = fmaf(wv.z, hv.z, acc.z); acc.w = fmaf(wv.w, hv.w, acc.w);
        }
        a1[tid] = fmaxf((acc.x + acc.y) + (acc.z + acc.w) + b1[tid], 0.f);
    }
    __syncthreads();
    if (tid < 3) {
        const float4* wr = (const float4*)(w2 + (size_t)tid * 128);
        const float4* aq = (const float4*)a1;
        float4 acc = make_float4(0.f, 0.f, 0.f, 0.f);
        #pragma unroll
        for (int k = 0; k < 32; ++k) {
            float4 wv = wr[k]; float4 av = aq[k];
            acc.x = fmaf(wv.x, av.x, acc.x); acc.y = fmaf(wv.y, av.y, acc.y);
            acc.z = fmaf(wv.z, av.z, acc.z); acc.w = fmaf(wv.w, av.w, acc.w);
        }
        lg[tid] = (acc.x + acc.y) + (acc.z + acc.w) + b2[tid];
    }
    __syncthreads();
    if (tid == 0) {
        float m = fmaxf(lg[0], fmaxf(lg[1], lg[2]));
        float e0 = __expf(lg[0] - m), e1 = __expf(lg[1] - m), e2 = __expf(lg[2] - m);
        float inv = 1.f / (e0 + e1 + e2);
        out[(size_t)s * 3 + 0] = e0 * inv;
        out[(size_t)s * 3 + 1] = e1 * inv;
        out[(size_t)s * 3 + 2] = e2 * inv;
    }
}

extern "C" void kernel_launch(void* const* d_in, const int* in_sizes, int n_in,
                              void* d_out, int out_size, void* d_ws, size_t ws_size,
                              hipStream_t stream) {
    (void)in_sizes; (void)n_in; (void)out_size; (void)ws_size;
    const float* x        = (const float*)d_in[0];
    const float* ea       = (const float*)d_in[1];
    const float* conv1_w  = (const float*)d_in[2];
    const float* conv1_b  = (const float*)d_in[3];
    const float* conv2_w  = (const float*)d_in[4];
    const float* conv2_b  = (const float*)d_in[5];
    const float* w_ih     = (const float*)d_in[6];
    const float* w_hh     = (const float*)d_in[7];
    const float* b_ih     = (const float*)d_in[8];
    const float* b_hh     = (const float*)d_in[9];
    const float* fc1_w    = (const float*)d_in[10];
    const float* fc1_b    = (const float*)d_in[11];
    const float* fc2_w    = (const float*)d_in[12];
    const float* fc2_b    = (const float*)d_in[13];
    const int*   ei       = (const int*)d_in[14];
    float* out = (float*)d_out;

    float* W    = (float*)d_ws;
    int2*  ent  = (int2*)(W + OFF_ENT);
    float* a1   = W + OFF_A1;
    float* g1   = W + OFF_G1;
    float* xg   = W + OFF_XG;
    int2*  ent2 = (int2*)(W + OFF_ENT2);
    float* h2   = W + OFF_H2;
    float* g2   = W + OFF_G2;
    int*   gcur = (int*)(W + OFF_GCUR);
    float* dis  = W + OFF_DIS;
    int2*  rng  = (int2*)(W + OFF_RNG);
    float* hl   = W + OFF_HL;
    float* st   = W + OFF_ST;

    // init + normalization stats (normalization itself fused into gather-1)
    init_zero<<<26, 256, 0, stream>>>(gcur, st);
    col_sums<<<1024, 256, 0, stream>>>(x, st);
    finalize_stats<<<1, 64, 0, stream>>>(st);

    // dest-sorted CSR via two-pass counting sort (coalesced writes, no global float atomics)
    part_kernel<<<NPART, 256, 0, stream>>>(ei, ea, gcur, ent2);
    bucket_csr<<<NBUK, 256, 0, stream>>>(ent2, gcur, ent, rng, dis);

    // GCN layer 1, commuted: a1 = S·normalize(x) (64 cols), then g1 = a1 @ W1 (96 cols)
    gcn_gather<16, true><<<NN * 16 / 256, 256, 0, stream>>>(x, rng, ent, dis, st, a1);
    gemm_tiled<64, 96, 32, 192, false, false, false><<<NN / 32, 192, 0, stream>>>(
        a1, conv1_w, nullptr, nullptr, nullptr, g1, 96);

    // GCN layer 2: h2 = relu(g1+b1) @ W2 (64 cols), then g2 = S·h2
    gemm_tiled<96, 64, 64, 256, true, false, false><<<NN / 64, 256, 0, stream>>>(
        g1, conv2_w, conv1_b, nullptr, nullptr, h2, 64);
    gcn_gather<16, false><<<NN * 16 / 256, 256, 0, stream>>>(h2, rng, ent, dis, nullptr, g2);

    // LSTM input transform: xg = relu(g2+b2) @ w_ih^T + b_ih + b_hh (both col-halves in one launch)
    gemm_tiled<64, 128, 32, 256, true, true, true><<<dim3(NN / 32, 2), 256, 0, stream>>>(
        g2, w_ih, conv2_b, b_ih, b_hh, xg, 256);

    // LSTM recurrence (8 seqs/block, 512 threads: dot pairs + activation threads)
    lstm_kernel<<<SS / 8, 512, 0, stream>>>(xg, w_hh, hl);

    // FC head + softmax
    head_kernel<<<SS, 128, 0, stream>>>(hl, fc1_w, fc1_b, fc2_w, fc2_b, out);
}